// Round 3
// baseline (445.832 us; speedup 1.0000x reference)
//
#include <hip/hip_runtime.h>

#define S_DIM 2048
#define D_DIM 64
#define BH    16
#define EPS_PRE  1e-5f
#define EPS_NORM 1e-12f
#define CT 8   // t-tiles (64 cols each) per chunk-block

// ---- workspace layout (float offsets) ----
#define WS_G   0                          // [16][32][64][64] per-tile Gram
#define WS_M   (BH*32*4096)               // [16][32][64][64] exclusive prefix
#define WS_GV  (2*BH*32*4096)             // [16][32][64] per-tile k-sum
#define WS_MV  (WS_GV + BH*32*64)         // [16][32][64] exclusive prefix k-sum
#define WS_RI  (WS_MV + BH*32*64)         // [16][2048] per-row 1/norm

typedef __attribute__((ext_vector_type(8))) short bf8;     // 8 x bf16 bit pattern
typedef __attribute__((ext_vector_type(4))) float f32x4;

static __device__ __forceinline__ unsigned fbits(float x){ union{float f;unsigned u;}v; v.f=x; return v.u; }
static __device__ __forceinline__ float bcast(unsigned u){ union{unsigned u;float f;}v; v.u=u; return v.f; }

static __device__ __forceinline__ void split2(float x, unsigned short& h, unsigned short& l){
  unsigned u = fbits(x);
  h = (unsigned short)(u >> 16);
  float lo = x - bcast(u & 0xffff0000u);
  l = (unsigned short)(fbits(lo) >> 16);
}

static __device__ __forceinline__ void pack4f(float x0, float x1, float x2, float x3,
                                              uint2& hh, uint2& ll){
  unsigned u0=fbits(x0),u1=fbits(x1),u2=fbits(x2),u3=fbits(x3);
  hh.x = (u0>>16) | (u1 & 0xffff0000u);
  hh.y = (u2>>16) | (u3 & 0xffff0000u);
  float l0 = x0 - bcast(u0&0xffff0000u);
  float l1 = x1 - bcast(u1&0xffff0000u);
  float l2 = x2 - bcast(u2&0xffff0000u);
  float l3 = x3 - bcast(u3&0xffff0000u);
  ll.x = (fbits(l0)>>16) | (fbits(l1)&0xffff0000u);
  ll.y = (fbits(l2)>>16) | (fbits(l3)&0xffff0000u);
}

static __device__ __forceinline__ f32x4 mfma16(bf8 a, bf8 b, f32x4 c){
  return __builtin_amdgcn_mfma_f32_16x16x32_bf16(a, b, c, 0, 0, 0);
}

// chunk id c in [0,80) -> (row-block rb 0..31, chunk ck)
static __device__ __forceinline__ void decode(int c, int& rb, int& ck){
  int g = 0;
  while (c >= 4*(g+1)*(g+2)) ++g;       // g = rb>>3 in 0..3
  const int off = c - 4*g*(g+1);
  const int nk = g + 1;
  const int q = off / nk;
  rb = g*8 + q;
  ck = off - q*nk;
}

// ============ K_gram: per-tile Gram G_i = K_i^T K_i, k-sums, zero fills ============
__global__ __launch_bounds__(256, 4)
void lka_gram(const float* __restrict__ Kg, float* __restrict__ ws,
              float* __restrict__ Og, float* __restrict__ Ag)
{
  __shared__ short tHi[4096], tLo[4096];   // K tile transposed [d][t]

  const int tid = threadIdx.x;
  const int wv  = tid >> 6;
  const int ln  = tid & 63;
  const int gq  = ln >> 4;
  const int i16 = ln & 15;

  const int blk = blockIdx.x;
  const int bh  = blk & 15;
  const int ti  = blk >> 4;                // tile 0..31

  const float* Kb = Kg + (size_t)bh * (S_DIM * D_DIM);

  // zero-init out slice (for K_emit atomics): 4096 floats per block
  {
    float4 z = make_float4(0.f,0.f,0.f,0.f);
    float4* p = (float4*)(Og + (size_t)blk * 4096);
    for (int c = tid; c < 1024; c += 256) p[c] = z;
  }
  // zero upper-triangle cols of row-block ti: [ (ti+1)*64, S )
  {
    const int c0 = (ti + 1) * 64;
    const int n4 = (S_DIM - c0) >> 2;
    float* rowp = Ag + (size_t)bh * S_DIM * S_DIM + (size_t)(ti*64 + (tid>>2)) * S_DIM + c0;
    float4 z = make_float4(0.f,0.f,0.f,0.f);
    for (int c = tid & 3; c < n4; c += 4) *(float4*)(rowp + 4*c) = z;
  }

  // stage K tile transposed: tHi/tLo[d][t], XOR-swizzled
  {
    const int d  = (tid & 31) * 2;
    const int tb = (tid >> 5) * 8;
    float2 rr[8];
    #pragma unroll
    for (int k = 0; k < 8; ++k)
      rr[k] = *(const float2*)(Kb + (size_t)(ti*64 + tb + k) * D_DIM + d);
    #pragma unroll
    for (int dd = 0; dd < 2; ++dd) {
      union { bf8 v; unsigned short h[8]; } H, L;
      #pragma unroll
      for (int k = 0; k < 8; ++k) split2(dd ? rr[k].y : rr[k].x, H.h[k], L.h[k]);
      const int dc = d + dd;
      const int idx = dc*64 + (tb ^ ((dc & 7) << 3));
      *(bf8*)&tHi[idx] = H.v;
      *(bf8*)&tLo[idx] = L.v;
    }
  }

  // per-tile k-sum (for the 2*eps cross term): coalesced over lanes
  float gsum = 0.f;
  if (tid < 64) {
    #pragma unroll 8
    for (int t = 0; t < 64; ++t) gsum += Kb[(size_t)(ti*64 + t) * D_DIM + tid];
  }
  __syncthreads();

  // G = K^T K, 3-product bf16 split; wave wv owns cols d2 = wv*16+i16
  const int d2 = wv*16 + i16;
  bf8 bhi[2], blo[2];
  #pragma unroll
  for (int ks = 0; ks < 2; ++ks) {
    const int bi = d2*64 + ((ks*32 + gq*8) ^ ((d2 & 7) << 3));
    bhi[ks] = *(const bf8*)&tHi[bi];
    blo[ks] = *(const bf8*)&tLo[bi];
  }
  f32x4 acc[4];
  #pragma unroll
  for (int rf = 0; rf < 4; ++rf) acc[rf] = (f32x4){0.f,0.f,0.f,0.f};
  #pragma unroll
  for (int ks = 0; ks < 2; ++ks) {
    #pragma unroll
    for (int rf = 0; rf < 4; ++rf) {
      const int d1 = rf*16 + i16;
      const int ai = d1*64 + ((ks*32 + gq*8) ^ ((d1 & 7) << 3));
      bf8 ahi = *(const bf8*)&tHi[ai];
      bf8 alo = *(const bf8*)&tLo[ai];
      acc[rf] = mfma16(ahi, bhi[ks], acc[rf]);
      acc[rf] = mfma16(alo, bhi[ks], acc[rf]);
      acc[rf] = mfma16(ahi, blo[ks], acc[rf]);
    }
  }
  // store G (symmetric): row = d2, col = d1-range
  float* Gp = ws + WS_G + (size_t)(bh*32 + ti) * 4096;
  #pragma unroll
  for (int rf = 0; rf < 4; ++rf)
    *(f32x4*)(Gp + d2*64 + rf*16 + gq*4) = acc[rf];

  if (tid < 64) ws[WS_GV + (size_t)(bh*32 + ti)*64 + tid] = gsum;
}

// ============ K_prefix: exclusive prefix sums of G and k-sums ============
__global__ __launch_bounds__(256, 8)
void lka_prefix(float* __restrict__ ws)
{
  const int tid = threadIdx.x;
  const int blk = blockIdx.x;          // 64 = 16 bh x 4 row-slices
  const int bh  = blk >> 2;
  const int r4  = blk & 3;

  const int row = r4*16 + (tid >> 4);
  const int c4  = (tid & 15) * 4;

  const float* Gp = ws + WS_G + (size_t)(bh*32)*4096 + row*64 + c4;
  float*       Mp = ws + WS_M + (size_t)(bh*32)*4096 + row*64 + c4;

  f32x4 acc = (f32x4){0.f,0.f,0.f,0.f};
  #pragma unroll 4
  for (int i = 0; i < 32; ++i) {
    *(f32x4*)(Mp + (size_t)i*4096) = acc;
    f32x4 g = *(const f32x4*)(Gp + (size_t)i*4096);
    acc[0]+=g[0]; acc[1]+=g[1]; acc[2]+=g[2]; acc[3]+=g[3];
  }

  if (r4 == 0 && tid < 64) {
    float a = 0.f;
    #pragma unroll 4
    for (int i = 0; i < 32; ++i) {
      ws[WS_MV + (size_t)(bh*32 + i)*64 + tid] = a;
      a += ws[WS_GV + (size_t)(bh*32 + i)*64 + tid];
    }
  }
}

// ============ K_rownorm: rinv per row via M-quadratic-form + diagonal tile ============
__global__ __launch_bounds__(256, 4)
void lka_rownorm(const float* __restrict__ Qg, const float* __restrict__ Kg,
                 float* __restrict__ ws)
{
  __shared__ short kHi[4096], kLo[4096];   // K diag tile [t][d]
  __shared__ short mHi[4096], mLo[4096];   // M prefix [d'][d]
  __shared__ float mvS[64];

  const int tid = threadIdx.x;
  const int wv  = tid >> 6;
  const int ln  = tid & 63;
  const int gq  = ln >> 4;
  const int i16 = ln & 15;

  const int blk = blockIdx.x;
  const int bh  = blk & 15;
  const int rb  = blk >> 4;
  const int s0  = rb * 64;

  const float* Qb = Qg + (size_t)bh * (S_DIM * D_DIM);
  const float* Kb = Kg + (size_t)bh * (S_DIM * D_DIM);

  const int srow = s0 + wv*16 + i16;

  // stage K diag tile [t][d] and M [d'][d], both hi/lo split + swizzle
  {
    const int r  = tid >> 2;
    const int db = (tid & 3) * 16;
    const float* kp = Kb + (size_t)(s0 + r) * D_DIM + db;
    const float* mp = ws + WS_M + (size_t)(bh*32 + rb)*4096 + r*64 + db;
    #pragma unroll
    for (int c = 0; c < 4; ++c) {
      float4 kv = *(const float4*)(kp + 4*c);
      uint2 hh, ll; pack4f(kv.x, kv.y, kv.z, kv.w, hh, ll);
      const int idx = r*64 + ((db + 4*c) ^ ((r & 7) << 3));
      *(uint2*)&kHi[idx] = hh;
      *(uint2*)&kLo[idx] = ll;
      float4 mv = *(const float4*)(mp + 4*c);
      uint2 mh, mlo; pack4f(mv.x, mv.y, mv.z, mv.w, mh, mlo);
      *(uint2*)&mHi[idx] = mh;
      *(uint2*)&mLo[idx] = mlo;
    }
  }
  if (tid < 64) mvS[tid] = ws[WS_MV + (size_t)(bh*32 + rb)*64 + tid];

  // q fragments (B operand)
  bf8 qhi[2], qlo[2];
  #pragma unroll
  for (int ks = 0; ks < 2; ++ks) {
    const float* qp = Qb + (size_t)srow * D_DIM + ks*32 + gq*8;
    float4 a = *(const float4*)qp;
    float4 b = *(const float4*)(qp + 4);
    union { bf8 v; unsigned short h[8]; } H, L;
    float f0[8] = {a.x,a.y,a.z,a.w,b.x,b.y,b.z,b.w};
    #pragma unroll
    for (int j = 0; j < 8; ++j) split2(f0[j], H.h[j], L.h[j]);
    qhi[ks] = H.v; qlo[ks] = L.v;
  }
  __syncthreads();

  // diag tile S^T and Y = M*q, both 3-product split
  f32x4 accS[4], accY[4];
  #pragma unroll
  for (int rf = 0; rf < 4; ++rf) { accS[rf] = (f32x4){0.f,0.f,0.f,0.f}; accY[rf] = (f32x4){0.f,0.f,0.f,0.f}; }
  #pragma unroll
  for (int ks = 0; ks < 2; ++ks) {
    #pragma unroll
    for (int rf = 0; rf < 4; ++rf) {
      const int r   = rf*16 + i16;
      const int idx = r*64 + ((ks*32 + gq*8) ^ ((r & 7) << 3));
      bf8 ahi = *(const bf8*)&kHi[idx];
      bf8 alo = *(const bf8*)&kLo[idx];
      accS[rf] = mfma16(ahi, qhi[ks], accS[rf]);
      accS[rf] = mfma16(alo, qhi[ks], accS[rf]);
      accS[rf] = mfma16(ahi, qlo[ks], accS[rf]);
      bf8 Ahi = *(const bf8*)&mHi[idx];
      bf8 Alo = *(const bf8*)&mLo[idx];
      accY[rf] = mfma16(Ahi, qhi[ks], accY[rf]);
      accY[rf] = mfma16(Alo, qhi[ks], accY[rf]);
      accY[rf] = mfma16(Ahi, qlo[ks], accY[rf]);
    }
  }

  // ssq = q.(Y + 2*eps*m) + diag causal partial
  float ssq = 0.f;
  #pragma unroll
  for (int rf = 0; rf < 4; ++rf) {
    f32x4 q4 = *(const f32x4*)(Qb + (size_t)srow * D_DIM + rf*16 + gq*4);
    f32x4 m4 = *(const f32x4*)&mvS[rf*16 + gq*4];
    #pragma unroll
    for (int rg = 0; rg < 4; ++rg) {
      ssq += q4[rg] * (accY[rf][rg] + 2.f*EPS_PRE*m4[rg]);
      const int t = s0 + rf*16 + gq*4 + rg;
      if (t <= srow) { const float x = accS[rf][rg] + EPS_PRE; ssq += x*x; }
    }
  }
  ssq += __shfl_xor(ssq, 16);
  ssq += __shfl_xor(ssq, 32);
  ssq += EPS_PRE*EPS_PRE * (float)(rb*64);
  ssq = fmaxf(ssq, 0.f);
  const float rinv = 1.f / fmaxf(sqrtf(ssq), EPS_NORM);
  if (gq == 0) ws[WS_RI + (size_t)bh*S_DIM + srow] = rinv;
}

// ============ K_emit: scale + stream attn + PV partials ============
__global__ __launch_bounds__(256, 3)
void lka_emit(const float* __restrict__ Qg, const float* __restrict__ Kg,
              const float* __restrict__ Vg, const float* __restrict__ ws,
              float* __restrict__ Og, float* __restrict__ Ag)
{
  __shared__ short kThi[4096], kTlo[4096];
  __shared__ short vThi[4096], vTlo[4096];
  __shared__ short pHi [4096], pLo [4096];

  const int tid = threadIdx.x;
  const int wv  = tid >> 6;
  const int ln  = tid & 63;
  const int gq  = ln >> 4;
  const int i16 = ln & 15;

  const int blk = blockIdx.x;
  const int bh  = blk & 15;
  int rb, ck; decode(blk >> 4, rb, ck);
  const int s0 = rb * 64;

  const float* Qb = Qg + (size_t)bh * (S_DIM * D_DIM);
  const float* Kb = Kg + (size_t)bh * (S_DIM * D_DIM);
  const float* Vb = Vg + (size_t)bh * (S_DIM * D_DIM);
  float* Ob = Og + (size_t)bh * (S_DIM * D_DIM);
  float* Ab = Ag + (size_t)bh * ((size_t)S_DIM * S_DIM);

  const int srow = s0 + wv*16 + i16;

  const float rinv = ws[WS_RI + (size_t)bh*S_DIM + srow];

  bf8 qhi[2], qlo[2];
  #pragma unroll
  for (int ks = 0; ks < 2; ++ks) {
    const float* qp = Qb + (size_t)srow * D_DIM + ks*32 + gq*8;
    float4 a = *(const float4*)qp;
    float4 b = *(const float4*)(qp + 4);
    union { bf8 v; unsigned short h[8]; } H, L;
    float f0[8] = {a.x,a.y,a.z,a.w,b.x,b.y,b.z,b.w};
    #pragma unroll
    for (int j = 0; j < 8; ++j) split2(f0[j], H.h[j], L.h[j]);
    qhi[ks] = H.v; qlo[ks] = L.v;
  }

  auto stageK = [&](int t0){
    const int t  = tid >> 2;
    const int db = (tid & 3) * 16;
    const float* kp = Kb + (size_t)(t0 + t) * D_DIM + db;
    #pragma unroll
    for (int c = 0; c < 4; ++c) {
      float4 kv = *(const float4*)(kp + 4*c);
      uint2 hh, ll; pack4f(kv.x, kv.y, kv.z, kv.w, hh, ll);
      const int idx = t*64 + ((db + 4*c) ^ ((t & 7) << 3));
      *(uint2*)&kThi[idx] = hh;
      *(uint2*)&kTlo[idx] = ll;
    }
  };
  auto stageV = [&](int t0){
    const int d  = (tid & 31) * 2;
    const int tb = (tid >> 5) * 8;
    float2 rr[8];
    #pragma unroll
    for (int k = 0; k < 8; ++k)
      rr[k] = *(const float2*)(Vb + (size_t)(t0 + tb + k) * D_DIM + d);
    #pragma unroll
    for (int dd = 0; dd < 2; ++dd) {
      union { bf8 v; unsigned short h[8]; } H, L;
      #pragma unroll
      for (int k = 0; k < 8; ++k) split2(dd ? rr[k].y : rr[k].x, H.h[k], L.h[k]);
      const int dc = d + dd;
      const int idx = dc*64 + (tb ^ ((dc & 7) << 3));
      *(bf8*)&vThi[idx] = H.v;
      *(bf8*)&vTlo[idx] = L.v;
    }
  };

  f32x4 oacc[4];
  #pragma unroll
  for (int rf = 0; rf < 4; ++rf) oacc[rf] = (f32x4){0.f,0.f,0.f,0.f};

  const int pR = wv*16 + i16;

  const int j0 = ck * CT;
  const int j1 = min(j0 + CT, rb + 1);
  for (int j = j0; j < j1; ++j) {
    __syncthreads();
    stageK(j * 64);
    stageV(j * 64);
    __syncthreads();

    f32x4 acc[4];
    #pragma unroll
    for (int rf = 0; rf < 4; ++rf) acc[rf] = (f32x4){0.f,0.f,0.f,0.f};
    #pragma unroll
    for (int ks = 0; ks < 2; ++ks) {
      #pragma unroll
      for (int rf = 0; rf < 4; ++rf) {
        const int t   = rf*16 + i16;
        const int idx = t*64 + ((ks*32 + gq*8) ^ ((t & 7) << 3));
        bf8 ahi = *(const bf8*)&kThi[idx];
        bf8 alo = *(const bf8*)&kTlo[idx];
        acc[rf] = mfma16(ahi, qhi[ks], acc[rf]);
        acc[rf] = mfma16(alo, qhi[ks], acc[rf]);
        acc[rf] = mfma16(ahi, qlo[ks], acc[rf]);
      }
    }

    #pragma unroll
    for (int rf = 0; rf < 4; ++rf) {
      f32x4 x;
      #pragma unroll
      for (int rg = 0; rg < 4; ++rg) {
        const int t = j*64 + rf*16 + gq*4 + rg;
        float v = acc[rf][rg] + EPS_PRE;
        if (j == rb && t > srow) v = 0.f;
        x[rg] = v * rinv;
      }
      *(f32x4*)(Ab + (size_t)srow * S_DIM + j*64 + rf*16 + gq*4) = x;
      uint2 hh, ll; pack4f(x[0], x[1], x[2], x[3], hh, ll);
      const int pidx = pR*64 + ((rf*16 + gq*4) ^ ((pR & 7) << 3));
      *(uint2*)&pHi[pidx] = hh;
      *(uint2*)&pLo[pidx] = ll;
    }

    #pragma unroll
    for (int ks = 0; ks < 2; ++ks) {
      const int pi = pR*64 + ((ks*32 + gq*8) ^ ((pR & 7) << 3));
      bf8 bhi = *(const bf8*)&pHi[pi];
      bf8 blo = *(const bf8*)&pLo[pi];
      #pragma unroll
      for (int rfd = 0; rfd < 4; ++rfd) {
        const int dct = rfd*16 + i16;
        const int vi  = dct*64 + ((ks*32 + gq*8) ^ ((dct & 7) << 3));
        bf8 ahi = *(const bf8*)&vThi[vi];
        bf8 alo = *(const bf8*)&vTlo[vi];
        oacc[rfd] = mfma16(ahi, bhi, oacc[rfd]);
        oacc[rfd] = mfma16(alo, bhi, oacc[rfd]);
        oacc[rfd] = mfma16(ahi, blo, oacc[rfd]);
      }
    }
  }

  #pragma unroll
  for (int rfd = 0; rfd < 4; ++rfd)
    #pragma unroll
    for (int rg = 0; rg < 4; ++rg)
      atomicAdd(&Ob[(size_t)srow * D_DIM + rfd*16 + gq*4 + rg], oacc[rfd][rg]);
}

extern "C" void kernel_launch(void* const* d_in, const int* in_sizes, int n_in,
                              void* d_out, int out_size, void* d_ws, size_t ws_size,
                              hipStream_t stream) {
  (void)in_sizes; (void)n_in; (void)out_size; (void)ws_size;
  const float* Q = (const float*)d_in[0];
  const float* K = (const float*)d_in[1];
  const float* V = (const float*)d_in[2];
  float* out  = (float*)d_out;
  float* attn = out + (size_t)BH * S_DIM * D_DIM;
  float* ws   = (float*)d_ws;

  lka_gram   <<<dim3(512),  dim3(256), 0, stream>>>(K, ws, out, attn);
  lka_prefix <<<dim3(64),   dim3(256), 0, stream>>>(ws);
  lka_rownorm<<<dim3(512),  dim3(256), 0, stream>>>(Q, K, ws);
  lka_emit   <<<dim3(BH*80),dim3(256), 0, stream>>>(Q, K, V, ws, out, attn);
}

// Round 4
// 437.571 us; speedup vs baseline: 1.0189x; 1.0189x over previous
//
#include <hip/hip_runtime.h>

#define S_DIM 2048
#define D_DIM 64
#define BH    16
#define EPS_PRE  1e-5f
#define EPS_NORM 1e-12f
#define CT 8   // t-tiles (64 cols each) per chunk-block

// ---- workspace layout (float offsets) ----
#define WS_G   0                          // [16][32][64][64] per-tile Gram
#define WS_M   (BH*32*4096)               // [16][32][64][64] exclusive prefix
#define WS_GV  (2*BH*32*4096)             // [16][32][64] per-tile k-sum
#define WS_MV  (WS_GV + BH*32*64)         // [16][32][64] exclusive prefix k-sum
#define WS_RI  (WS_MV + BH*32*64)         // [16][2048] per-row 1/norm
#define FRAG_F (BH*32*2048)               // floats per fragment blob (16bh x 32tile x 8frag x 64ln x 8bf16)
#define WS_KAH (WS_RI + BH*2048)
#define WS_KAL (WS_KAH + FRAG_F)
#define WS_VAH (WS_KAL + FRAG_F)
#define WS_VAL (WS_VAH + FRAG_F)

typedef __attribute__((ext_vector_type(8))) short bf8;     // 8 x bf16 bit pattern
typedef __attribute__((ext_vector_type(4))) float f32x4;

static __device__ __forceinline__ unsigned fbits(float x){ union{float f;unsigned u;}v; v.f=x; return v.u; }
static __device__ __forceinline__ float bcast(unsigned u){ union{unsigned u;float f;}v; v.u=u; return v.f; }

static __device__ __forceinline__ void split2(float x, unsigned short& h, unsigned short& l){
  unsigned u = fbits(x);
  h = (unsigned short)(u >> 16);
  float lo = x - bcast(u & 0xffff0000u);
  l = (unsigned short)(fbits(lo) >> 16);
}

static __device__ __forceinline__ void pack4f(float x0, float x1, float x2, float x3,
                                              uint2& hh, uint2& ll){
  unsigned u0=fbits(x0),u1=fbits(x1),u2=fbits(x2),u3=fbits(x3);
  hh.x = (u0>>16) | (u1 & 0xffff0000u);
  hh.y = (u2>>16) | (u3 & 0xffff0000u);
  float l0 = x0 - bcast(u0&0xffff0000u);
  float l1 = x1 - bcast(u1&0xffff0000u);
  float l2 = x2 - bcast(u2&0xffff0000u);
  float l3 = x3 - bcast(u3&0xffff0000u);
  ll.x = (fbits(l0)>>16) | (fbits(l1)&0xffff0000u);
  ll.y = (fbits(l2)>>16) | (fbits(l3)&0xffff0000u);
}

static __device__ __forceinline__ f32x4 mfma16(bf8 a, bf8 b, f32x4 c){
  return __builtin_amdgcn_mfma_f32_16x16x32_bf16(a, b, c, 0, 0, 0);
}

// chunk id c in [0,80) -> (row-block rb 0..31, chunk ck)
static __device__ __forceinline__ void decode(int c, int& rb, int& ck){
  int g = 0;
  while (c >= 4*(g+1)*(g+2)) ++g;       // g = rb>>3 in 0..3
  const int off = c - 4*g*(g+1);
  const int nk = g + 1;
  const int q = off / nk;
  rb = g*8 + q;
  ck = off - q*nk;
}

// ============ K_pack: pre-split K (A-layout [t][d]) and V^T (A-layout [d][t]) into
// bf16 hi/lo fragment blobs in exact MFMA lane order ============
__global__ __launch_bounds__(256, 4)
void lka_pack(const float* __restrict__ Kg, const float* __restrict__ Vg,
              float* __restrict__ ws)
{
  __shared__ short kHi[4096], kLo[4096];   // K tile [t][d] swizzled
  __shared__ short vHi[4096], vLo[4096];   // V^T tile [d][t] swizzled

  const int tid = threadIdx.x;
  const int blk = blockIdx.x;
  const int bh  = blk & 15;
  const int ti  = blk >> 4;

  const float* Kb = Kg + (size_t)bh * (S_DIM * D_DIM);
  const float* Vb = Vg + (size_t)bh * (S_DIM * D_DIM);

  // stage K [t][d]
  {
    const int t  = tid >> 2;
    const int db = (tid & 3) * 16;
    const float* kp = Kb + (size_t)(ti*64 + t) * D_DIM + db;
    #pragma unroll
    for (int c = 0; c < 4; ++c) {
      float4 kv = *(const float4*)(kp + 4*c);
      uint2 hh, ll; pack4f(kv.x, kv.y, kv.z, kv.w, hh, ll);
      const int idx = t*64 + ((db + 4*c) ^ ((t & 7) << 3));
      *(uint2*)&kHi[idx] = hh;
      *(uint2*)&kLo[idx] = ll;
    }
  }
  // stage V^T [d][t]
  {
    const int d  = (tid & 31) * 2;
    const int tb = (tid >> 5) * 8;
    float2 rr[8];
    #pragma unroll
    for (int k = 0; k < 8; ++k)
      rr[k] = *(const float2*)(Vb + (size_t)(ti*64 + tb + k) * D_DIM + d);
    #pragma unroll
    for (int dd = 0; dd < 2; ++dd) {
      union { bf8 v; unsigned short h[8]; } H, L;
      #pragma unroll
      for (int k = 0; k < 8; ++k) split2(dd ? rr[k].y : rr[k].x, H.h[k], L.h[k]);
      const int dc = d + dd;
      const int idx = dc*64 + (tb ^ ((dc & 7) << 3));
      *(bf8*)&vHi[idx] = H.v;
      *(bf8*)&vLo[idx] = L.v;
    }
  }
  __syncthreads();

  const int w = tid >> 6, ln = tid & 63, gq = ln >> 4, i16 = ln & 15;
  short* KAh = (short*)(ws + WS_KAH);
  short* KAl = (short*)(ws + WS_KAL);
  short* VAh = (short*)(ws + WS_VAH);
  short* VAl = (short*)(ws + WS_VAL);

  #pragma unroll
  for (int ff = 0; ff < 2; ++ff) {
    const int f  = w*2 + ff;          // f = ks*4 + rf
    const int ks = f >> 2, rf = f & 3;
    const int r   = rf*16 + i16;
    const int idx = r*64 + ((ks*32 + gq*8) ^ ((r & 7) << 3));
    const size_t o = ((size_t)(bh*32 + ti)*8 + f)*512 + ln*8;
    *(bf8*)(KAh + o) = *(const bf8*)&kHi[idx];
    *(bf8*)(KAl + o) = *(const bf8*)&kLo[idx];
    *(bf8*)(VAh + o) = *(const bf8*)&vHi[idx];
    *(bf8*)(VAl + o) = *(const bf8*)&vLo[idx];
  }
}

// ============ K_gram: per-tile Gram G_i = K_i^T K_i, k-sums, zero fills ============
__global__ __launch_bounds__(256, 4)
void lka_gram(const float* __restrict__ Kg, float* __restrict__ ws,
              float* __restrict__ Og, float* __restrict__ Ag)
{
  __shared__ short tHi[4096], tLo[4096];   // K tile transposed [d][t]

  const int tid = threadIdx.x;
  const int wv  = tid >> 6;
  const int ln  = tid & 63;
  const int gq  = ln >> 4;
  const int i16 = ln & 15;

  const int blk = blockIdx.x;
  const int bh  = blk & 15;
  const int ti  = blk >> 4;                // tile 0..31

  const float* Kb = Kg + (size_t)bh * (S_DIM * D_DIM);

  // zero-init out slice (for K_emit atomics): 4096 floats per block
  {
    f32x4 z = (f32x4){0.f,0.f,0.f,0.f};
    f32x4* p = (f32x4*)(Og + (size_t)blk * 4096);
    for (int c = tid; c < 1024; c += 256) p[c] = z;
  }
  // zero upper-triangle cols of row-block ti: [ (ti+1)*64, S )
  {
    const int c0 = (ti + 1) * 64;
    const int n4 = (S_DIM - c0) >> 2;
    float* rowp = Ag + (size_t)bh * S_DIM * S_DIM + (size_t)(ti*64 + (tid>>2)) * S_DIM + c0;
    f32x4 z = (f32x4){0.f,0.f,0.f,0.f};
    for (int c = tid & 3; c < n4; c += 4)
      __builtin_nontemporal_store(z, (f32x4*)(rowp + 4*c));
  }

  // stage K tile transposed: tHi/tLo[d][t], XOR-swizzled
  {
    const int d  = (tid & 31) * 2;
    const int tb = (tid >> 5) * 8;
    float2 rr[8];
    #pragma unroll
    for (int k = 0; k < 8; ++k)
      rr[k] = *(const float2*)(Kb + (size_t)(ti*64 + tb + k) * D_DIM + d);
    #pragma unroll
    for (int dd = 0; dd < 2; ++dd) {
      union { bf8 v; unsigned short h[8]; } H, L;
      #pragma unroll
      for (int k = 0; k < 8; ++k) split2(dd ? rr[k].y : rr[k].x, H.h[k], L.h[k]);
      const int dc = d + dd;
      const int idx = dc*64 + (tb ^ ((dc & 7) << 3));
      *(bf8*)&tHi[idx] = H.v;
      *(bf8*)&tLo[idx] = L.v;
    }
  }

  // per-tile k-sum
  float gsum = 0.f;
  if (tid < 64) {
    #pragma unroll 8
    for (int t = 0; t < 64; ++t) gsum += Kb[(size_t)(ti*64 + t) * D_DIM + tid];
  }
  __syncthreads();

  // G = K^T K, 3-product bf16 split; wave wv owns cols d2 = wv*16+i16
  const int d2 = wv*16 + i16;
  bf8 bhi[2], blo[2];
  #pragma unroll
  for (int ks = 0; ks < 2; ++ks) {
    const int bi = d2*64 + ((ks*32 + gq*8) ^ ((d2 & 7) << 3));
    bhi[ks] = *(const bf8*)&tHi[bi];
    blo[ks] = *(const bf8*)&tLo[bi];
  }
  f32x4 acc[4];
  #pragma unroll
  for (int rf = 0; rf < 4; ++rf) acc[rf] = (f32x4){0.f,0.f,0.f,0.f};
  #pragma unroll
  for (int ks = 0; ks < 2; ++ks) {
    #pragma unroll
    for (int rf = 0; rf < 4; ++rf) {
      const int d1 = rf*16 + i16;
      const int ai = d1*64 + ((ks*32 + gq*8) ^ ((d1 & 7) << 3));
      bf8 ahi = *(const bf8*)&tHi[ai];
      bf8 alo = *(const bf8*)&tLo[ai];
      acc[rf] = mfma16(ahi, bhi[ks], acc[rf]);
      acc[rf] = mfma16(alo, bhi[ks], acc[rf]);
      acc[rf] = mfma16(ahi, blo[ks], acc[rf]);
    }
  }
  float* Gp = ws + WS_G + (size_t)(bh*32 + ti) * 4096;
  #pragma unroll
  for (int rf = 0; rf < 4; ++rf)
    *(f32x4*)(Gp + d2*64 + rf*16 + gq*4) = acc[rf];

  if (tid < 64) ws[WS_GV + (size_t)(bh*32 + ti)*64 + tid] = gsum;
}

// ============ K_prefix: exclusive prefix sums of G and k-sums ============
__global__ __launch_bounds__(256, 8)
void lka_prefix(float* __restrict__ ws)
{
  const int tid = threadIdx.x;
  const int blk = blockIdx.x;          // 64 = 16 bh x 4 row-slices
  const int bh  = blk >> 2;
  const int r4  = blk & 3;

  const int row = r4*16 + (tid >> 4);
  const int c4  = (tid & 15) * 4;

  const float* Gp = ws + WS_G + (size_t)(bh*32)*4096 + row*64 + c4;
  float*       Mp = ws + WS_M + (size_t)(bh*32)*4096 + row*64 + c4;

  f32x4 acc = (f32x4){0.f,0.f,0.f,0.f};
  #pragma unroll 4
  for (int i = 0; i < 32; ++i) {
    *(f32x4*)(Mp + (size_t)i*4096) = acc;
    f32x4 g = *(const f32x4*)(Gp + (size_t)i*4096);
    acc[0]+=g[0]; acc[1]+=g[1]; acc[2]+=g[2]; acc[3]+=g[3];
  }

  if (r4 == 0 && tid < 64) {
    float a = 0.f;
    #pragma unroll 4
    for (int i = 0; i < 32; ++i) {
      ws[WS_MV + (size_t)(bh*32 + i)*64 + tid] = a;
      a += ws[WS_GV + (size_t)(bh*32 + i)*64 + tid];
    }
  }
}

// ============ K_rownorm: rinv per row via M-quadratic-form + diagonal tile ============
__global__ __launch_bounds__(256, 4)
void lka_rownorm(const float* __restrict__ Qg, const float* __restrict__ Kg,
                 float* __restrict__ ws)
{
  __shared__ short kHi[4096], kLo[4096];   // K diag tile [t][d]
  __shared__ short mHi[4096], mLo[4096];   // M prefix [d'][d]
  __shared__ float mvS[64];

  const int tid = threadIdx.x;
  const int wv  = tid >> 6;
  const int ln  = tid & 63;
  const int gq  = ln >> 4;
  const int i16 = ln & 15;

  const int blk = blockIdx.x;
  const int bh  = blk & 15;
  const int rb  = blk >> 4;
  const int s0  = rb * 64;

  const float* Qb = Qg + (size_t)bh * (S_DIM * D_DIM);
  const float* Kb = Kg + (size_t)bh * (S_DIM * D_DIM);

  const int srow = s0 + wv*16 + i16;

  {
    const int r  = tid >> 2;
    const int db = (tid & 3) * 16;
    const float* kp = Kb + (size_t)(s0 + r) * D_DIM + db;
    const float* mp = ws + WS_M + (size_t)(bh*32 + rb)*4096 + r*64 + db;
    #pragma unroll
    for (int c = 0; c < 4; ++c) {
      float4 kv = *(const float4*)(kp + 4*c);
      uint2 hh, ll; pack4f(kv.x, kv.y, kv.z, kv.w, hh, ll);
      const int idx = r*64 + ((db + 4*c) ^ ((r & 7) << 3));
      *(uint2*)&kHi[idx] = hh;
      *(uint2*)&kLo[idx] = ll;
      float4 mv = *(const float4*)(mp + 4*c);
      uint2 mh, mlo; pack4f(mv.x, mv.y, mv.z, mv.w, mh, mlo);
      *(uint2*)&mHi[idx] = mh;
      *(uint2*)&mLo[idx] = mlo;
    }
  }
  if (tid < 64) mvS[tid] = ws[WS_MV + (size_t)(bh*32 + rb)*64 + tid];

  bf8 qhi[2], qlo[2];
  #pragma unroll
  for (int ks = 0; ks < 2; ++ks) {
    const float* qp = Qb + (size_t)srow * D_DIM + ks*32 + gq*8;
    float4 a = *(const float4*)qp;
    float4 b = *(const float4*)(qp + 4);
    union { bf8 v; unsigned short h[8]; } H, L;
    float f0[8] = {a.x,a.y,a.z,a.w,b.x,b.y,b.z,b.w};
    #pragma unroll
    for (int j = 0; j < 8; ++j) split2(f0[j], H.h[j], L.h[j]);
    qhi[ks] = H.v; qlo[ks] = L.v;
  }
  __syncthreads();

  f32x4 accS[4], accY[4];
  #pragma unroll
  for (int rf = 0; rf < 4; ++rf) { accS[rf] = (f32x4){0.f,0.f,0.f,0.f}; accY[rf] = (f32x4){0.f,0.f,0.f,0.f}; }
  #pragma unroll
  for (int ks = 0; ks < 2; ++ks) {
    #pragma unroll
    for (int rf = 0; rf < 4; ++rf) {
      const int r   = rf*16 + i16;
      const int idx = r*64 + ((ks*32 + gq*8) ^ ((r & 7) << 3));
      bf8 ahi = *(const bf8*)&kHi[idx];
      bf8 alo = *(const bf8*)&kLo[idx];
      accS[rf] = mfma16(ahi, qhi[ks], accS[rf]);
      accS[rf] = mfma16(alo, qhi[ks], accS[rf]);
      accS[rf] = mfma16(ahi, qlo[ks], accS[rf]);
      bf8 Ahi = *(const bf8*)&mHi[idx];
      bf8 Alo = *(const bf8*)&mLo[idx];
      accY[rf] = mfma16(Ahi, qhi[ks], accY[rf]);
      accY[rf] = mfma16(Alo, qhi[ks], accY[rf]);
      accY[rf] = mfma16(Ahi, qlo[ks], accY[rf]);
    }
  }

  float ssq = 0.f;
  #pragma unroll
  for (int rf = 0; rf < 4; ++rf) {
    f32x4 q4 = *(const f32x4*)(Qb + (size_t)srow * D_DIM + rf*16 + gq*4);
    f32x4 m4 = *(const f32x4*)&mvS[rf*16 + gq*4];
    #pragma unroll
    for (int rg = 0; rg < 4; ++rg) {
      ssq += q4[rg] * (accY[rf][rg] + 2.f*EPS_PRE*m4[rg]);
      const int t = s0 + rf*16 + gq*4 + rg;
      if (t <= srow) { const float x = accS[rf][rg] + EPS_PRE; ssq += x*x; }
    }
  }
  ssq += __shfl_xor(ssq, 16);
  ssq += __shfl_xor(ssq, 32);
  ssq += EPS_PRE*EPS_PRE * (float)(rb*64);
  ssq = fmaxf(ssq, 0.f);
  const float rinv = 1.f / fmaxf(sqrtf(ssq), EPS_NORM);
  if (gq == 0) ws[WS_RI + (size_t)bh*S_DIM + srow] = rinv;
}

// ============ K_emit: barrier-free — A-frags direct from blobs, P per-wave LDS ============
__global__ __launch_bounds__(256, 4)
void lka_emit(const float* __restrict__ Qg, const float* __restrict__ ws,
              float* __restrict__ Og, float* __restrict__ Ag)
{
  __shared__ short pHi[4096], pLo[4096];

  const int tid = threadIdx.x;
  const int wv  = tid >> 6;
  const int ln  = tid & 63;
  const int gq  = ln >> 4;
  const int i16 = ln & 15;

  const int blk = blockIdx.x;
  const int bh  = blk & 15;
  int rb, ck; decode(blk >> 4, rb, ck);
  const int s0 = rb * 64;

  const float* Qb = Qg + (size_t)bh * (S_DIM * D_DIM);
  float* Ob = Og + (size_t)bh * (S_DIM * D_DIM);
  float* Ab = Ag + (size_t)bh * ((size_t)S_DIM * S_DIM);

  const int srow = s0 + wv*16 + i16;

  const float rinv = ws[WS_RI + (size_t)bh*S_DIM + srow];

  const short* KAh = (const short*)(ws + WS_KAH);
  const short* KAl = (const short*)(ws + WS_KAL);
  const short* VAh = (const short*)(ws + WS_VAH);
  const short* VAl = (const short*)(ws + WS_VAL);

  bf8 qhi[2], qlo[2];
  #pragma unroll
  for (int ks = 0; ks < 2; ++ks) {
    const float* qp = Qb + (size_t)srow * D_DIM + ks*32 + gq*8;
    float4 a = *(const float4*)qp;
    float4 b = *(const float4*)(qp + 4);
    union { bf8 v; unsigned short h[8]; } H, L;
    float f0[8] = {a.x,a.y,a.z,a.w,b.x,b.y,b.z,b.w};
    #pragma unroll
    for (int j = 0; j < 8; ++j) split2(f0[j], H.h[j], L.h[j]);
    qhi[ks] = H.v; qlo[ks] = L.v;
  }

  f32x4 oacc[4];
  #pragma unroll
  for (int rf = 0; rf < 4; ++rf) oacc[rf] = (f32x4){0.f,0.f,0.f,0.f};

  const int pR = wv*16 + i16;

  const int j0 = ck * CT;
  const int j1 = min(j0 + CT, rb + 1);
  for (int j = j0; j < j1; ++j) {
    const size_t tb = ((size_t)(bh*32 + j)*8)*512 + ln*8;  // frag base (shorts)

    // ---- QK: A-frags straight from K blob ----
    f32x4 acc[4];
    #pragma unroll
    for (int rf = 0; rf < 4; ++rf) acc[rf] = (f32x4){0.f,0.f,0.f,0.f};
    #pragma unroll
    for (int ks = 0; ks < 2; ++ks) {
      #pragma unroll
      for (int rf = 0; rf < 4; ++rf) {
        const size_t o = tb + (size_t)(ks*4 + rf)*512;
        bf8 ahi = *(const bf8*)(KAh + o);
        bf8 alo = *(const bf8*)(KAl + o);
        acc[rf] = mfma16(ahi, qhi[ks], acc[rf]);
        acc[rf] = mfma16(alo, qhi[ks], acc[rf]);
        acc[rf] = mfma16(ahi, qlo[ks], acc[rf]);
      }
    }

    // ---- scale, stream attn (nontemporal), pack P to per-wave LDS ----
    #pragma unroll
    for (int rf = 0; rf < 4; ++rf) {
      f32x4 x;
      #pragma unroll
      for (int rg = 0; rg < 4; ++rg) {
        const int t = j*64 + rf*16 + gq*4 + rg;
        float v = acc[rf][rg] + EPS_PRE;
        if (j == rb && t > srow) v = 0.f;
        x[rg] = v * rinv;
      }
      __builtin_nontemporal_store(x, (f32x4*)(Ab + (size_t)srow * S_DIM + j*64 + rf*16 + gq*4));
      uint2 hh, ll; pack4f(x[0], x[1], x[2], x[3], hh, ll);
      const int pidx = pR*64 + ((rf*16 + gq*4) ^ ((pR & 7) << 3));
      *(uint2*)&pHi[pidx] = hh;
      *(uint2*)&pLo[pidx] = ll;
    }

    // ---- PV: A-frags straight from V blob, B from per-wave P (intra-wave only) ----
    #pragma unroll
    for (int ks = 0; ks < 2; ++ks) {
      const int pi = pR*64 + ((ks*32 + gq*8) ^ ((pR & 7) << 3));
      bf8 bhi = *(const bf8*)&pHi[pi];
      bf8 blo = *(const bf8*)&pLo[pi];
      #pragma unroll
      for (int rfd = 0; rfd < 4; ++rfd) {
        const size_t o = tb + (size_t)(ks*4 + rfd)*512;
        bf8 ahi = *(const bf8*)(VAh + o);
        bf8 alo = *(const bf8*)(VAl + o);
        oacc[rfd] = mfma16(ahi, bhi, oacc[rfd]);
        oacc[rfd] = mfma16(alo, bhi, oacc[rfd]);
        oacc[rfd] = mfma16(ahi, blo, oacc[rfd]);
      }
    }
  }

  #pragma unroll
  for (int rfd = 0; rfd < 4; ++rfd)
    #pragma unroll
    for (int rg = 0; rg < 4; ++rg)
      atomicAdd(&Ob[(size_t)srow * D_DIM + rfd*16 + gq*4 + rg], oacc[rfd][rg]);
}

extern "C" void kernel_launch(void* const* d_in, const int* in_sizes, int n_in,
                              void* d_out, int out_size, void* d_ws, size_t ws_size,
                              hipStream_t stream) {
  (void)in_sizes; (void)n_in; (void)out_size; (void)ws_size;
  const float* Q = (const float*)d_in[0];
  const float* K = (const float*)d_in[1];
  const float* V = (const float*)d_in[2];
  float* out  = (float*)d_out;
  float* attn = out + (size_t)BH * S_DIM * D_DIM;
  float* ws   = (float*)d_ws;

  lka_pack   <<<dim3(512),  dim3(256), 0, stream>>>(K, V, ws);
  lka_gram   <<<dim3(512),  dim3(256), 0, stream>>>(K, ws, out, attn);
  lka_prefix <<<dim3(64),   dim3(256), 0, stream>>>(ws);
  lka_rownorm<<<dim3(512),  dim3(256), 0, stream>>>(Q, K, ws);
  lka_emit   <<<dim3(BH*80),dim3(256), 0, stream>>>(Q, ws, out, attn);
}

// Round 6
// 404.328 us; speedup vs baseline: 1.1027x; 1.0822x over previous
//
#include <hip/hip_runtime.h>

#define S_DIM 2048
#define D_DIM 64
#define BH    16
#define EPS_PRE  1e-5f
#define EPS_NORM 1e-12f
#define CT 8   // t-tiles (64 cols) per emit chunk

#define TILE_F 4096
#define FRAG_F (BH*32*2048)               // floats per blob half (hi or lo)
// ---- workspace layout (float offsets) ----
#define WS_G   0
#define WS_W   (WS_G  + BH*32*TILE_F)
#define WS_M   (WS_W  + BH*32*TILE_F)
#define WS_WP  (WS_M  + BH*32*TILE_F)
#define WS_GV  (WS_WP + BH*32*TILE_F)
#define WS_VV  (WS_GV + BH*32*64)
#define WS_MV  (WS_VV + BH*32*64)
#define WS_UV  (WS_MV + BH*32*64)
#define WS_RI  (WS_UV + BH*32*64)
#define WS_KAH (WS_RI + BH*2048)
#define WS_KAL (WS_KAH + FRAG_F)

typedef __attribute__((ext_vector_type(8))) short bf8;
typedef __attribute__((ext_vector_type(4))) float f32x4;

static __device__ __forceinline__ unsigned fbits(float x){ union{float f;unsigned u;}v; v.f=x; return v.u; }
static __device__ __forceinline__ float bcast(unsigned u){ union{unsigned u;float f;}v; v.u=u; return v.f; }

static __device__ __forceinline__ void split2(float x, unsigned short& h, unsigned short& l){
  unsigned u = fbits(x);
  h = (unsigned short)(u >> 16);
  float lo = x - bcast(u & 0xffff0000u);
  l = (unsigned short)(fbits(lo) >> 16);
}

static __device__ __forceinline__ void pack4f(float x0, float x1, float x2, float x3,
                                              uint2& hh, uint2& ll){
  unsigned u0=fbits(x0),u1=fbits(x1),u2=fbits(x2),u3=fbits(x3);
  hh.x = (u0>>16) | (u1 & 0xffff0000u);
  hh.y = (u2>>16) | (u3 & 0xffff0000u);
  float l0 = x0 - bcast(u0&0xffff0000u);
  float l1 = x1 - bcast(u1&0xffff0000u);
  float l2 = x2 - bcast(u2&0xffff0000u);
  float l3 = x3 - bcast(u3&0xffff0000u);
  ll.x = (fbits(l0)>>16) | (fbits(l1)&0xffff0000u);
  ll.y = (fbits(l2)>>16) | (fbits(l3)&0xffff0000u);
}

static __device__ __forceinline__ f32x4 mfma16(bf8 a, bf8 b, f32x4 c){
  return __builtin_amdgcn_mfma_f32_16x16x32_bf16(a, b, c, 0, 0, 0);
}

static __device__ __forceinline__ void decode(int c, int& rb, int& ck){
  int g = 0;
  while (c >= 4*(g+1)*(g+2)) ++g;
  const int off = c - 4*g*(g+1);
  const int nk = g + 1;
  const int q = off / nk;
  rb = g*8 + q;
  ck = off - q*nk;
}

// ===== prep: stage K,V tiles; G=K^T K and W (PV prefix op) MFMAs; K blob; sums; zero fill =====
__global__ __launch_bounds__(256, 3)
void lka_prep(const float* __restrict__ Kg, const float* __restrict__ Vg,
              float* __restrict__ ws, float* __restrict__ Ag)
{
  __shared__ short kTh[4096], kTl[4096];   // K^T tile [d][t]
  __shared__ short vTh[4096], vTl[4096];   // V^T tile [d][t]
  __shared__ short kRh[4096], kRl[4096];   // K tile  [t][d]

  const int tid = threadIdx.x;
  const int wv  = tid >> 6;
  const int ln  = tid & 63;
  const int gq  = ln >> 4;
  const int i16 = ln & 15;

  const int blk = blockIdx.x;
  const int bh  = blk & 15;
  const int ti  = blk >> 4;

  const float* Kb = Kg + (size_t)bh * (S_DIM * D_DIM);
  const float* Vb = Vg + (size_t)bh * (S_DIM * D_DIM);

  // zero upper-triangle attn cols [ (ti+1)*64, S ) for 64 rows of row-block ti
  {
    const int c0 = (ti + 1) * 64;
    const int n4 = (S_DIM - c0) >> 2;
    float* rowp = Ag + (size_t)bh * S_DIM * S_DIM + (size_t)(ti*64 + (tid>>2)) * S_DIM + c0;
    f32x4 z = (f32x4){0.f,0.f,0.f,0.f};
    for (int c = tid & 3; c < n4; c += 4)
      __builtin_nontemporal_store(z, (f32x4*)(rowp + 4*c));
  }

  // stage K^T and V^T [d][t]
  {
    const int d  = (tid & 31) * 2;
    const int tb = (tid >> 5) * 8;
    float2 kr[8], vr[8];
    #pragma unroll
    for (int k = 0; k < 8; ++k) {
      kr[k] = *(const float2*)(Kb + (size_t)(ti*64 + tb + k) * D_DIM + d);
      vr[k] = *(const float2*)(Vb + (size_t)(ti*64 + tb + k) * D_DIM + d);
    }
    #pragma unroll
    for (int dd = 0; dd < 2; ++dd) {
      union { bf8 v; unsigned short h[8]; } KH, KL, VH, VL;
      #pragma unroll
      for (int k = 0; k < 8; ++k) {
        split2(dd ? kr[k].y : kr[k].x, KH.h[k], KL.h[k]);
        split2(dd ? vr[k].y : vr[k].x, VH.h[k], VL.h[k]);
      }
      const int dc = d + dd;
      const int idx = dc*64 + (tb ^ ((dc & 7) << 3));
      *(bf8*)&kTh[idx] = KH.v; *(bf8*)&kTl[idx] = KL.v;
      *(bf8*)&vTh[idx] = VH.v; *(bf8*)&vTl[idx] = VL.v;
    }
  }
  // stage K [t][d]
  {
    const int t  = tid >> 2;
    const int db = (tid & 3) * 16;
    const float* kp = Kb + (size_t)(ti*64 + t) * D_DIM + db;
    #pragma unroll
    for (int c = 0; c < 4; ++c) {
      float4 kv = *(const float4*)(kp + 4*c);
      uint2 hh, ll; pack4f(kv.x, kv.y, kv.z, kv.w, hh, ll);
      const int idx = t*64 + ((db + 4*c) ^ ((t & 7) << 3));
      *(uint2*)&kRh[idx] = hh;
      *(uint2*)&kRl[idx] = ll;
    }
  }
  // per-tile k-sum / v-sum
  float gsum = 0.f, vsum = 0.f;
  if (tid < 64) {
    #pragma unroll 8
    for (int t = 0; t < 64; ++t) {
      gsum += Kb[(size_t)(ti*64 + t) * D_DIM + tid];
      vsum += Vb[(size_t)(ti*64 + t) * D_DIM + tid];
    }
  }
  __syncthreads();

  // B-frags: kT row d2 and vT row d2 (d2 = wv*16+i16)
  const int d2 = wv*16 + i16;
  bf8 bkh[2], bkl[2], bvh[2], bvl[2];
  #pragma unroll
  for (int ks = 0; ks < 2; ++ks) {
    const int bi = d2*64 + ((ks*32 + gq*8) ^ ((d2 & 7) << 3));
    bkh[ks] = *(const bf8*)&kTh[bi]; bkl[ks] = *(const bf8*)&kTl[bi];
    bvh[ks] = *(const bf8*)&vTh[bi]; bvl[ks] = *(const bf8*)&vTl[bi];
  }
  f32x4 accG[4], accW[4];
  #pragma unroll
  for (int rf = 0; rf < 4; ++rf) { accG[rf]=(f32x4){0,0,0,0}; accW[rf]=(f32x4){0,0,0,0}; }
  #pragma unroll
  for (int ks = 0; ks < 2; ++ks) {
    #pragma unroll
    for (int rf = 0; rf < 4; ++rf) {
      const int d1 = rf*16 + i16;
      const int ai = d1*64 + ((ks*32 + gq*8) ^ ((d1 & 7) << 3));
      bf8 ahi = *(const bf8*)&kTh[ai];
      bf8 alo = *(const bf8*)&kTl[ai];
      accG[rf] = mfma16(ahi, bkh[ks], accG[rf]);
      accG[rf] = mfma16(alo, bkh[ks], accG[rf]);
      accG[rf] = mfma16(ahi, bkl[ks], accG[rf]);
      // W_mem[dv][dk] = sum_t K[t][dk] V[t][dv]  (A=kT rows dk, B=vT col dv)
      accW[rf] = mfma16(ahi, bvh[ks], accW[rf]);
      accW[rf] = mfma16(alo, bvh[ks], accW[rf]);
      accW[rf] = mfma16(ahi, bvl[ks], accW[rf]);
    }
  }
  float* Gp = ws + WS_G + (size_t)(bh*32 + ti) * TILE_F;
  float* Wp = ws + WS_W + (size_t)(bh*32 + ti) * TILE_F;
  #pragma unroll
  for (int rf = 0; rf < 4; ++rf) {
    *(f32x4*)(Gp + d2*64 + rf*16 + gq*4) = accG[rf];
    *(f32x4*)(Wp + d2*64 + rf*16 + gq*4) = accW[rf];
  }
  if (tid < 64) {
    ws[WS_GV + (size_t)(bh*32 + ti)*64 + tid] = gsum;
    ws[WS_VV + (size_t)(bh*32 + ti)*64 + tid] = vsum;
  }

  // K blob (A-layout frags, lane order)
  short* KAh = (short*)(ws + WS_KAH);
  short* KAl = (short*)(ws + WS_KAL);
  #pragma unroll
  for (int ff = 0; ff < 2; ++ff) {
    const int f  = wv*2 + ff;
    const int ks = f >> 2, rf = f & 3;
    const int r   = rf*16 + i16;
    const int idx = r*64 + ((ks*32 + gq*8) ^ ((r & 7) << 3));
    const size_t o = ((size_t)(bh*32 + ti)*8 + f)*512 + ln*8;
    *(bf8*)(KAh + o) = *(const bf8*)&kRh[idx];
    *(bf8*)(KAl + o) = *(const bf8*)&kRl[idx];
  }
}

// ===== prefix: exclusive prefix of G->M, W->WP, sums =====
__global__ __launch_bounds__(256, 8)
void lka_prefix(float* __restrict__ ws)
{
  const int tid = threadIdx.x;
  const int blk = blockIdx.x;          // 128 = 16 bh x 2 sel x 4 slices
  const int bh  = blk >> 3;
  const int sel = (blk >> 2) & 1;
  const int r4  = blk & 3;

  const int row = r4*16 + (tid >> 4);
  const int c4  = (tid & 15) * 4;

  const float* Sp = ws + (sel ? WS_W : WS_G) + (size_t)(bh*32)*TILE_F + row*64 + c4;
  float*       Dp = ws + (sel ? WS_WP : WS_M) + (size_t)(bh*32)*TILE_F + row*64 + c4;

  f32x4 acc = (f32x4){0.f,0.f,0.f,0.f};
  #pragma unroll 4
  for (int i = 0; i < 32; ++i) {
    *(f32x4*)(Dp + (size_t)i*TILE_F) = acc;
    f32x4 g = *(const f32x4*)(Sp + (size_t)i*TILE_F);
    acc[0]+=g[0]; acc[1]+=g[1]; acc[2]+=g[2]; acc[3]+=g[3];
  }

  if (r4 == 0 && tid < 64) {
    const int so = sel ? WS_VV : WS_GV;
    const int doo = sel ? WS_UV : WS_MV;
    float a = 0.f;
    #pragma unroll 4
    for (int i = 0; i < 32; ++i) {
      ws[doo + (size_t)(bh*32 + i)*64 + tid] = a;
      a += ws[so + (size_t)(bh*32 + i)*64 + tid];
    }
  }
}

// ===== rownorm_out: rinv (M-quadratic form + diag) AND out (W-prefix + diag PV) =====
__global__ __launch_bounds__(256, 3)
void lka_rno(const float* __restrict__ Qg, const float* __restrict__ Vg,
             float* __restrict__ ws, float* __restrict__ Og)
{
  __shared__ short aH[4096], aL[4096];   // M rows, then WP rows
  __shared__ short vTh[4096], vTl[4096]; // V^T diag tile [d][t]
  __shared__ short pH[4096], pL[4096];   // P diag (unnormalized)
  __shared__ float mvS[64], uvS[64];

  const int tid = threadIdx.x;
  const int wv  = tid >> 6;
  const int ln  = tid & 63;
  const int gq  = ln >> 4;
  const int i16 = ln & 15;

  const int blk = blockIdx.x;
  const int bh  = blk & 15;
  const int rb  = blk >> 4;
  const int s0  = rb * 64;

  const float* Qb = Qg + (size_t)bh * (S_DIM * D_DIM);
  const float* Vb = Vg + (size_t)bh * (S_DIM * D_DIM);
  float* Ob = Og + (size_t)bh * (S_DIM * D_DIM);

  const int srow = s0 + wv*16 + i16;
  const int pR   = wv*16 + i16;

  // stage M rows
  {
    const int r  = tid >> 2;
    const int db = (tid & 3) * 16;
    const float* mp = ws + WS_M + (size_t)(bh*32 + rb)*TILE_F + r*64 + db;
    #pragma unroll
    for (int c = 0; c < 4; ++c) {
      float4 mv = *(const float4*)(mp + 4*c);
      uint2 hh, ll; pack4f(mv.x, mv.y, mv.z, mv.w, hh, ll);
      const int idx = r*64 + ((db + 4*c) ^ ((r & 7) << 3));
      *(uint2*)&aH[idx] = hh;
      *(uint2*)&aL[idx] = ll;
    }
  }
  // stage V^T diag tile
  {
    const int d  = (tid & 31) * 2;
    const int tb = (tid >> 5) * 8;
    float2 rr[8];
    #pragma unroll
    for (int k = 0; k < 8; ++k)
      rr[k] = *(const float2*)(Vb + (size_t)(s0 + tb + k) * D_DIM + d);
    #pragma unroll
    for (int dd = 0; dd < 2; ++dd) {
      union { bf8 v; unsigned short h[8]; } H, L;
      #pragma unroll
      for (int k = 0; k < 8; ++k) split2(dd ? rr[k].y : rr[k].x, H.h[k], L.h[k]);
      const int dc = d + dd;
      const int idx = dc*64 + (tb ^ ((dc & 7) << 3));
      *(bf8*)&vTh[idx] = H.v;
      *(bf8*)&vTl[idx] = L.v;
    }
  }
  if (tid < 64) {
    mvS[tid] = ws[WS_MV + (size_t)(bh*32 + rb)*64 + tid];
    uvS[tid] = ws[WS_UV + (size_t)(bh*32 + rb)*64 + tid];
  }

  // q frags + diag K blob frags
  bf8 qhi[2], qlo[2];
  #pragma unroll
  for (int ks = 0; ks < 2; ++ks) {
    const float* qp = Qb + (size_t)srow * D_DIM + ks*32 + gq*8;
    float4 a = *(const float4*)qp;
    float4 b = *(const float4*)(qp + 4);
    union { bf8 v; unsigned short h[8]; } H, L;
    float f0[8] = {a.x,a.y,a.z,a.w,b.x,b.y,b.z,b.w};
    #pragma unroll
    for (int j = 0; j < 8; ++j) split2(f0[j], H.h[j], L.h[j]);
    qhi[ks] = H.v; qlo[ks] = L.v;
  }
  const short* KAh = (const short*)(ws + WS_KAH);
  const short* KAl = (const short*)(ws + WS_KAL);
  const size_t tb0 = ((size_t)(bh*32 + rb)*8)*512 + ln*8;
  __syncthreads();

  // diag S^T and Y = M q
  f32x4 accS[4], accY[4];
  #pragma unroll
  for (int rf = 0; rf < 4; ++rf) { accS[rf]=(f32x4){0,0,0,0}; accY[rf]=(f32x4){0,0,0,0}; }
  #pragma unroll
  for (int ks = 0; ks < 2; ++ks) {
    #pragma unroll
    for (int rf = 0; rf < 4; ++rf) {
      const size_t o = tb0 + (size_t)(ks*4 + rf)*512;
      bf8 khi = *(const bf8*)(KAh + o);
      bf8 klo = *(const bf8*)(KAl + o);
      accS[rf] = mfma16(khi, qhi[ks], accS[rf]);
      accS[rf] = mfma16(klo, qhi[ks], accS[rf]);
      accS[rf] = mfma16(khi, qlo[ks], accS[rf]);
      const int r   = rf*16 + i16;
      const int idx = r*64 + ((ks*32 + gq*8) ^ ((r & 7) << 3));
      bf8 mhi = *(const bf8*)&aH[idx];
      bf8 mlo = *(const bf8*)&aL[idx];
      accY[rf] = mfma16(mhi, qhi[ks], accY[rf]);
      accY[rf] = mfma16(mlo, qhi[ks], accY[rf]);
      accY[rf] = mfma16(mhi, qlo[ks], accY[rf]);
    }
  }

  // ssq + P pack (unnormalized, masked, +eps)
  float ssq = 0.f;
  #pragma unroll
  for (int rf = 0; rf < 4; ++rf) {
    f32x4 q4 = *(const f32x4*)(Qb + (size_t)srow * D_DIM + rf*16 + gq*4);
    f32x4 m4 = *(const f32x4*)&mvS[rf*16 + gq*4];
    f32x4 x;
    #pragma unroll
    for (int rg = 0; rg < 4; ++rg) {
      ssq += q4[rg] * (accY[rf][rg] + 2.f*EPS_PRE*m4[rg]);
      const int t = s0 + rf*16 + gq*4 + rg;
      float v = (t <= srow) ? (accS[rf][rg] + EPS_PRE) : 0.f;
      ssq += v * v;
      x[rg] = v;
    }
    uint2 hh, ll; pack4f(x[0], x[1], x[2], x[3], hh, ll);
    const int pidx = pR*64 + ((rf*16 + gq*4) ^ ((pR & 7) << 3));
    *(uint2*)&pH[pidx] = hh;
    *(uint2*)&pL[pidx] = ll;
  }
  ssq += __shfl_xor(ssq, 16);
  ssq += __shfl_xor(ssq, 32);
  ssq += EPS_PRE*EPS_PRE * (float)(rb*64);
  ssq = fmaxf(ssq, 0.f);
  const float rinv = 1.f / fmaxf(sqrtf(ssq), EPS_NORM);
  if (gq == 0) ws[WS_RI + (size_t)bh*S_DIM + srow] = rinv;

  __syncthreads();
  // restage aH/aL = WP rows
  {
    const int r  = tid >> 2;
    const int db = (tid & 3) * 16;
    const float* wp = ws + WS_WP + (size_t)(bh*32 + rb)*TILE_F + r*64 + db;
    #pragma unroll
    for (int c = 0; c < 4; ++c) {
      float4 wv4 = *(const float4*)(wp + 4*c);
      uint2 hh, ll; pack4f(wv4.x, wv4.y, wv4.z, wv4.w, hh, ll);
      const int idx = r*64 + ((db + 4*c) ^ ((r & 7) << 3));
      *(uint2*)&aH[idx] = hh;
      *(uint2*)&aL[idx] = ll;
    }
  }
  __syncthreads();

  // out = rinv * ( WP^T-row form + eps*u + diag PV )
  f32x4 accO[4];
  #pragma unroll
  for (int rf = 0; rf < 4; ++rf) accO[rf]=(f32x4){0,0,0,0};
  #pragma unroll
  for (int ks = 0; ks < 2; ++ks) {
    const int pi = pR*64 + ((ks*32 + gq*8) ^ ((pR & 7) << 3));
    bf8 bph = *(const bf8*)&pH[pi];
    bf8 bpl = *(const bf8*)&pL[pi];
    #pragma unroll
    for (int rf = 0; rf < 4; ++rf) {
      const int r   = rf*16 + i16;
      const int idx = r*64 + ((ks*32 + gq*8) ^ ((r & 7) << 3));
      bf8 whi = *(const bf8*)&aH[idx];
      bf8 wlo = *(const bf8*)&aL[idx];
      accO[rf] = mfma16(whi, qhi[ks], accO[rf]);
      accO[rf] = mfma16(wlo, qhi[ks], accO[rf]);
      accO[rf] = mfma16(whi, qlo[ks], accO[rf]);
      bf8 vhi = *(const bf8*)&vTh[idx];
      bf8 vlo = *(const bf8*)&vTl[idx];
      accO[rf] = mfma16(vhi, bph, accO[rf]);
      accO[rf] = mfma16(vlo, bph, accO[rf]);
      accO[rf] = mfma16(vhi, bpl, accO[rf]);
    }
  }
  #pragma unroll
  for (int rf = 0; rf < 4; ++rf) {
    f32x4 u4 = *(const f32x4*)&uvS[rf*16 + gq*4];
    f32x4 o4;
    #pragma unroll
    for (int rg = 0; rg < 4; ++rg)
      o4[rg] = rinv * (accO[rf][rg] + EPS_PRE * u4[rg]);
    *(f32x4*)(Ob + (size_t)srow * D_DIM + rf*16 + gq*4) = o4;
  }
}

// ===== emit: lean QK -> scale -> stream attn. No LDS, no barriers, no atomics =====
__global__ __launch_bounds__(256, 4)
void lka_emit(const float* __restrict__ Qg, const float* __restrict__ ws,
              float* __restrict__ Ag)
{
  const int tid = threadIdx.x;
  const int wv  = tid >> 6;
  const int ln  = tid & 63;
  const int gq  = ln >> 4;
  const int i16 = ln & 15;

  const int blk = blockIdx.x;
  const int bh  = blk & 15;
  int rb, ck; decode(blk >> 4, rb, ck);
  const int s0 = rb * 64;

  const float* Qb = Qg + (size_t)bh * (S_DIM * D_DIM);
  float* Ab = Ag + (size_t)bh * ((size_t)S_DIM * S_DIM);

  const int srow = s0 + wv*16 + i16;
  const float rinv = ws[WS_RI + (size_t)bh*S_DIM + srow];

  const short* KAh = (const short*)(ws + WS_KAH);
  const short* KAl = (const short*)(ws + WS_KAL);

  bf8 qhi[2], qlo[2];
  #pragma unroll
  for (int ks = 0; ks < 2; ++ks) {
    const float* qp = Qb + (size_t)srow * D_DIM + ks*32 + gq*8;
    float4 a = *(const float4*)qp;
    float4 b = *(const float4*)(qp + 4);
    union { bf8 v; unsigned short h[8]; } H, L;
    float f0[8] = {a.x,a.y,a.z,a.w,b.x,b.y,b.z,b.w};
    #pragma unroll
    for (int j = 0; j < 8; ++j) split2(f0[j], H.h[j], L.h[j]);
    qhi[ks] = H.v; qlo[ks] = L.v;
  }

  float* Arow = Ab + (size_t)srow * S_DIM + gq*4;

  const int j0 = ck * CT;
  const int j1 = min(j0 + CT, rb + 1);
  #pragma unroll 2
  for (int j = j0; j < j1; ++j) {
    const size_t tb = ((size_t)(bh*32 + j)*8)*512 + ln*8;

    f32x4 acc[4];
    #pragma unroll
    for (int rf = 0; rf < 4; ++rf) acc[rf] = (f32x4){0.f,0.f,0.f,0.f};
    #pragma unroll
    for (int ks = 0; ks < 2; ++ks) {
      #pragma unroll
      for (int rf = 0; rf < 4; ++rf) {
        const size_t o = tb + (size_t)(ks*4 + rf)*512;
        bf8 ahi = *(const bf8*)(KAh + o);
        bf8 alo = *(const bf8*)(KAl + o);
        acc[rf] = mfma16(ahi, qhi[ks], acc[rf]);
        acc[rf] = mfma16(alo, qhi[ks], acc[rf]);
        acc[rf] = mfma16(ahi, qlo[ks], acc[rf]);
      }
    }

    if (j == rb) {
      #pragma unroll
      for (int rf = 0; rf < 4; ++rf) {
        f32x4 x;
        #pragma unroll
        for (int rg = 0; rg < 4; ++rg) {
          const int t = j*64 + rf*16 + gq*4 + rg;
          x[rg] = (t <= srow) ? (acc[rf][rg] + EPS_PRE) * rinv : 0.f;
        }
        __builtin_nontemporal_store(x, (f32x4*)(Arow + j*64 + rf*16));
      }
    } else {
      #pragma unroll
      for (int rf = 0; rf < 4; ++rf) {
        f32x4 x;
        #pragma unroll
        for (int rg = 0; rg < 4; ++rg)
          x[rg] = (acc[rf][rg] + EPS_PRE) * rinv;
        __builtin_nontemporal_store(x, (f32x4*)(Arow + j*64 + rf*16));
      }
    }
  }
}

extern "C" void kernel_launch(void* const* d_in, const int* in_sizes, int n_in,
                              void* d_out, int out_size, void* d_ws, size_t ws_size,
                              hipStream_t stream) {
  (void)in_sizes; (void)n_in; (void)out_size; (void)ws_size;
  const float* Q = (const float*)d_in[0];
  const float* K = (const float*)d_in[1];
  const float* V = (const float*)d_in[2];
  float* out  = (float*)d_out;
  float* attn = out + (size_t)BH * S_DIM * D_DIM;
  float* ws   = (float*)d_ws;

  lka_prep  <<<dim3(512),   dim3(256), 0, stream>>>(K, V, ws, attn);
  lka_prefix<<<dim3(128),   dim3(256), 0, stream>>>(ws);
  lka_rno   <<<dim3(512),   dim3(256), 0, stream>>>(Q, V, ws, out);
  lka_emit  <<<dim3(BH*80), dim3(256), 0, stream>>>(Q, ws, attn);
}